// Round 5
// baseline (385.607 us; speedup 1.0000x reference)
//
#include <hip/hip_runtime.h>
#include <math.h>

#define BB   16
#define NN   2048
#define DIN  512
#define DKK  10
#define NHD  2
#define DH   5
#define HID  20
#define DOUT 512
#define BH   32          // BB*NHD
#define KC   256         // attention k-chunk
#define NKC  8           // NN/KC
#define PCK  128         // proj W chunk rows staged in LDS

// ws layout (floats):
//   qkv  : [3][BH][NN][8]   (q pre-scaled by 1/sqrt(5); rows padded 5->8)
//   part : [NKC][BH][NN][8] (acc[0..4], denom at [5])
//   Wpack: [512][32]        (Wq|Wk|Wv rows packed+padded, 128B-aligned rows)
//   h1   : [B*N][20]        overlays qkv (dead after attn) -> no ws growth
#define QKV_ELEMS  ((size_t)3*BH*NN*8)
#define PART_ELEMS ((size_t)NKC*BH*NN*8)

// ---------------------------------------------------------------- kernel 0
// Pack Wq|Wk|Wv into [512][32] rows (cols 0-9 q, 10-19 k, 20-29 v, 30-31 zero)
__global__ __launch_bounds__(256) void pack_w_kernel(
    const float* __restrict__ Wq, const float* __restrict__ Wk,
    const float* __restrict__ Wv, float* __restrict__ Wpack)
{
    const int idx = blockIdx.x*256 + threadIdx.x;   // 0..16383
    const int j = idx >> 5, c = idx & 31;
    float v = 0.f;
    if (c < 10)      v = Wq[j*DKK + c];
    else if (c < 20) v = Wk[j*DKK + (c-10)];
    else if (c < 30) v = Wv[j*DKK + (c-20)];
    Wpack[idx] = v;
}

// ---------------------------------------------------------------- kernel 1
// One TOKEN PER THREAD. x row in registers (16-dim double-buffered groups),
// W chunk [128][32] in LDS read as wave-uniform broadcasts (conflict-free).
// acc[30] fully statically indexed -> ~85 VGPR, no spill possible.
__global__ __launch_bounds__(256) void proj_kernel(
    const float* __restrict__ x, const float* __restrict__ Wpack,
    const float* __restrict__ bq, const float* __restrict__ bk,
    const float* __restrict__ bv, float* __restrict__ qkv)
{
    __shared__ float ws[PCK*32];    // 16 KB
    const int t   = threadIdx.x;
    const int tok = blockIdx.x*256 + t;
    const float* xr = x + (size_t)tok*DIN;

    float acc[30];
    #pragma unroll
    for (int o=0;o<30;o++) acc[o]=0.f;

    for (int ch=0; ch<DIN/PCK; ++ch){
        __syncthreads();
        const float4* wsrc = (const float4*)(Wpack + (size_t)ch*PCK*32);
        #pragma unroll
        for (int i=0;i<4;i++) ((float4*)ws)[t + i*256] = wsrc[t + i*256];
        __syncthreads();

        const float* xc = xr + ch*PCK;
        float4 xa0=*(const float4*)(xc+ 0), xa1=*(const float4*)(xc+ 4),
               xa2=*(const float4*)(xc+ 8), xa3=*(const float4*)(xc+12);
        #pragma unroll
        for (int g=0; g<PCK/16; ++g){
            float4 xb0,xb1,xb2,xb3;
            if (g < PCK/16-1){
                const float* p = xc + (g+1)*16;
                xb0=*(const float4*)(p+ 0); xb1=*(const float4*)(p+ 4);
                xb2=*(const float4*)(p+ 8); xb3=*(const float4*)(p+12);
            }
            const float xs16[16] = {xa0.x,xa0.y,xa0.z,xa0.w, xa1.x,xa1.y,xa1.z,xa1.w,
                                    xa2.x,xa2.y,xa2.z,xa2.w, xa3.x,xa3.y,xa3.z,xa3.w};
            #pragma unroll
            for (int j=0;j<16;j++){
                const float xj = xs16[j];
                const float* wrow = ws + (g*16+j)*32;   // uniform -> broadcast
                #pragma unroll
                for (int o=0;o<30;o++) acc[o] = fmaf(xj, wrow[o], acc[o]);
            }
            if (g < PCK/16-1){ xa0=xb0; xa1=xb1; xa2=xb2; xa3=xb3; }
        }
    }

    const float qs = 0.44721359549995793f;          // 1/sqrt(5) folded into Q
    const int b = tok >> 11;
    const int n = tok & (NN-1);
    #pragma unroll
    for (int c=0;c<30;c++){
        const int mat = c / 10;
        const int d10 = c - mat*10;
        const int h   = d10 / 5;
        const int dd  = d10 - h*5;
        float v = acc[c] + ((mat==0) ? bq[d10] : (mat==1) ? bk[d10] : bv[d10]);
        if (mat==0) v *= qs;
        qkv[(size_t)mat*BH*NN*8 + (((size_t)(b*NHD+h))*NN + n)*8 + dd] = v;
    }
}

// ---------------------------------------------------------------- kernel 2
// Block 256 = 4 waves = 256 q-rows; K/V chunk (256x8 each) staged in LDS
// (contiguous -> perfectly coalesced), inner loop reads are wave-uniform
// LDS broadcasts (conflict-free) instead of R4's serial L2 scalar loads.
// scores = sin(q.k/sqrt5) in [-1,1] -> exp needs no max pass.
__global__ __launch_bounds__(256) void attn_kernel(
    const float* __restrict__ qkv, float* __restrict__ part)
{
    __shared__ float Ks[KC*8];      // 8 KB
    __shared__ float Vs[KC*8];      // 8 KB
    const int qt = blockIdx.x;      // 0..7 (256 q rows each)
    const int kc = blockIdx.y;      // 0..7
    const int bh = blockIdx.z;
    const int k0 = kc*KC;
    const int qblk0 = qt*256;
    if (k0 > qblk0 + 255) return;   // uniform causal early-out

    const int t    = threadIdx.x;
    const int lane = t & 63;
    const int w    = t >> 6;

    const float* kbase = qkv + (size_t)BH*NN*8 + ((size_t)bh*NN + k0)*8;
    const float* vbase = kbase + (size_t)BH*NN*8;
    ((float4*)Ks)[t]     = ((const float4*)kbase)[t];
    ((float4*)Ks)[t+256] = ((const float4*)kbase)[t+256];
    ((float4*)Vs)[t]     = ((const float4*)vbase)[t];
    ((float4*)Vs)[t+256] = ((const float4*)vbase)[t+256];
    __syncthreads();

    const int q = qblk0 + w*64 + lane;
    const float* qr = qkv + ((size_t)bh*NN + q)*8;
    const float4 qv = *(const float4*)qr;
    const float  q4 = qr[4];
    // wave-uniform iteration count (full KC for sub-diagonal blocks)
    const int kend = min(KC, qblk0 + (w+1)*64 - k0);

    float denom=0.f, a0=0.f, a1=0.f, a2=0.f, a3=0.f, a4=0.f;
    #pragma unroll 4
    for (int kk=0; kk<kend; ++kk){
        const float4 kv = *(const float4*)(Ks + kk*8);  // broadcast
        const float  k4 = Ks[kk*8+4];
        const float4 vv = *(const float4*)(Vs + kk*8);
        const float  v4 = Vs[kk*8+4];
        float s = qv.x*kv.x + qv.y*kv.y + qv.z*kv.z + qv.w*kv.w + q4*k4;
        float e = __expf(__sinf(s));
        e = (k0+kk <= q) ? e : 0.f;                     // causal mask
        denom += e;
        a0 = fmaf(e, vv.x, a0);
        a1 = fmaf(e, vv.y, a1);
        a2 = fmaf(e, vv.z, a2);
        a3 = fmaf(e, vv.w, a3);
        a4 = fmaf(e, v4,   a4);
    }
    float* pr = part + (((size_t)kc*BH + bh)*NN + q)*8;
    *(float4*)pr = make_float4(a0,a1,a2,a3);
    pr[4] = a4;
    pr[5] = denom;
}

// ---------------------------------------------------------------- kernel 3a
// One TOKEN PER LANE: part-reduce + Wm1 + leaky_relu, write h1[tok][20].
__global__ __launch_bounds__(256) void h1_kernel(
    const float* __restrict__ part,
    const float* __restrict__ Wm1, const float* __restrict__ bm1,
    float* __restrict__ h1buf)
{
    const int tok = blockIdx.x*256 + threadIdx.x;   // 0..32767
    const int b   = tok >> 11;
    const int n   = tok & (NN-1);
    const int nc  = (n >> 8) + 1;                   // valid causal k-chunks

    float vals[DKK];
    #pragma unroll
    for (int h=0;h<NHD;h++){
        const int bh = b*NHD + h;
        float s0=0,s1=0,s2=0,s3=0,s4=0,sd=0;
        for (int c=0;c<nc;c++){
            const float* pr = part + (((size_t)c*BH + bh)*NN + n)*8;
            const float4 p0 = *(const float4*)pr;
            const float4 p1 = *(const float4*)(pr+4);
            s0+=p0.x; s1+=p0.y; s2+=p0.z; s3+=p0.w; s4+=p1.x; sd+=p1.y;
        }
        const float inv = 1.0f / sd;
        vals[h*DH+0]=s0*inv; vals[h*DH+1]=s1*inv; vals[h*DH+2]=s2*inv;
        vals[h*DH+3]=s3*inv; vals[h*DH+4]=s4*inv;
    }

    float h1[HID];
    #pragma unroll
    for (int jo=0;jo<HID;jo++){
        float t = bm1[jo];
        #pragma unroll
        for (int d=0;d<DKK;d++) t = fmaf(vals[d], Wm1[d*HID+jo], t);
        h1[jo] = (t > 0.f) ? t : 0.01f*t;
    }
    float* hr = h1buf + (size_t)tok*HID;            // 80B rows, 16B-aligned
    #pragma unroll
    for (int j5=0;j5<5;j5++)
        *(float4*)(hr + j5*4) = make_float4(h1[j5*4+0],h1[j5*4+1],h1[j5*4+2],h1[j5*4+3]);
}

// ---------------------------------------------------------------- kernel 3b
// One wave = half an output row (256 cols, 4/lane) for 8 tokens; Wm2 slice
// in registers; per token: 20 uniform h1 loads + 80 FMA + dwordx4 store.
__global__ __launch_bounds__(256) void out_kernel(
    const float* __restrict__ h1buf,
    const float* __restrict__ Wm2, const float* __restrict__ bm2,
    float* __restrict__ out)
{
    const int wave = threadIdx.x >> 6;
    const int lane = threadIdx.x & 63;
    const int unit = blockIdx.x*4 + wave;   // 0..8191
    const int hc   = unit & 1;
    const int tg   = unit >> 1;
    const int o0   = hc*256 + lane*4;

    float4 w2[HID];
    #pragma unroll
    for (int j=0;j<HID;j++) w2[j] = *(const float4*)(Wm2 + j*DOUT + o0);
    const float4 b2 = *(const float4*)(bm2 + o0);

    for (int ti=0; ti<8; ++ti){
        const int tok = tg*8 + ti;
        const float* hr = h1buf + (size_t)tok*HID;  // wave-uniform
        float4 acc = b2;
        #pragma unroll
        for (int j5=0;j5<5;j5++){
            const float4 hv = *(const float4*)(hr + j5*4);
            const float h0=hv.x, h1v=hv.y, h2=hv.z, h3=hv.w;
            acc.x = fmaf(h0, w2[j5*4+0].x, acc.x);
            acc.y = fmaf(h0, w2[j5*4+0].y, acc.y);
            acc.z = fmaf(h0, w2[j5*4+0].z, acc.z);
            acc.w = fmaf(h0, w2[j5*4+0].w, acc.w);
            acc.x = fmaf(h1v, w2[j5*4+1].x, acc.x);
            acc.y = fmaf(h1v, w2[j5*4+1].y, acc.y);
            acc.z = fmaf(h1v, w2[j5*4+1].z, acc.z);
            acc.w = fmaf(h1v, w2[j5*4+1].w, acc.w);
            acc.x = fmaf(h2, w2[j5*4+2].x, acc.x);
            acc.y = fmaf(h2, w2[j5*4+2].y, acc.y);
            acc.z = fmaf(h2, w2[j5*4+2].z, acc.z);
            acc.w = fmaf(h2, w2[j5*4+2].w, acc.w);
            acc.x = fmaf(h3, w2[j5*4+3].x, acc.x);
            acc.y = fmaf(h3, w2[j5*4+3].y, acc.y);
            acc.z = fmaf(h3, w2[j5*4+3].z, acc.z);
            acc.w = fmaf(h3, w2[j5*4+3].w, acc.w);
        }
        *(float4*)(out + (size_t)tok*DOUT + o0) = acc;
    }
}

// ---------------------------------------------------------------- launch
extern "C" void kernel_launch(void* const* d_in, const int* in_sizes, int n_in,
                              void* d_out, int out_size, void* d_ws, size_t ws_size,
                              hipStream_t stream) {
    const float* x   = (const float*)d_in[0];
    const float* Wq  = (const float*)d_in[1];
    const float* bq  = (const float*)d_in[2];
    const float* Wk  = (const float*)d_in[3];
    const float* bk  = (const float*)d_in[4];
    const float* Wv  = (const float*)d_in[5];
    const float* bv  = (const float*)d_in[6];
    const float* Wm1 = (const float*)d_in[7];
    const float* bm1 = (const float*)d_in[8];
    const float* Wm2 = (const float*)d_in[9];
    const float* bm2 = (const float*)d_in[10];
    float* out = (float*)d_out;

    float* qkv   = (float*)d_ws;
    float* part  = qkv + QKV_ELEMS;
    float* Wpack = part + PART_ELEMS;
    float* h1buf = qkv;   // overlays qkv: dead after attn_kernel (stream-ordered)

    pack_w_kernel<<<dim3(64), dim3(256), 0, stream>>>(Wq, Wk, Wv, Wpack);
    proj_kernel<<<dim3(128), dim3(256), 0, stream>>>(x, Wpack, bq, bk, bv, qkv);
    attn_kernel<<<dim3(NN/256, NKC, BH), dim3(256), 0, stream>>>(qkv, part);
    h1_kernel<<<dim3(128), dim3(256), 0, stream>>>(part, Wm1, bm1, h1buf);
    out_kernel<<<dim3(2048), dim3(256), 0, stream>>>(h1buf, Wm2, bm2, out);
}

// Round 6
// 274.279 us; speedup vs baseline: 1.4059x; 1.4059x over previous
//
#include <hip/hip_runtime.h>
#include <math.h>

#define BB   16
#define NN   2048
#define DIN  512
#define DKK  10
#define NHD  2
#define DH   5
#define HID  20
#define DOUT 512
#define BH   32          // BB*NHD
#define KC   256         // attention k-chunk
#define NKC  8           // NN/KC
#define PC   64          // proj dim-chunk staged in LDS
#define QB   512         // attn q rows per block

// ws layout (floats):
//   qkv  : [3][BH][NN][8]   (q pre-scaled by 1/sqrt(5); rows padded 5->8)
//   part : [NKC][BH][NN][8] (acc[0..4], denom at [5])
//   Wpack: [512][32]        (Wq|Wk|Wv rows packed+padded, 128B-aligned rows)
//   h1   : [B*N][20]        overlays qkv (dead after attn) -> no ws growth
#define QKV_ELEMS  ((size_t)3*BH*NN*8)
#define PART_ELEMS ((size_t)NKC*BH*NN*8)

// ---------------------------------------------------------------- kernel 0
// Pack Wq|Wk|Wv into [512][32] rows (cols 0-9 q, 10-19 k, 20-29 v, 30-31 zero)
__global__ __launch_bounds__(256) void pack_w_kernel(
    const float* __restrict__ Wq, const float* __restrict__ Wk,
    const float* __restrict__ Wv, float* __restrict__ Wpack)
{
    const int idx = blockIdx.x*256 + threadIdx.x;   // 0..16383
    const int j = idx >> 5, c = idx & 31;
    float v = 0.f;
    if (c < 10)      v = Wq[j*DKK + c];
    else if (c < 20) v = Wk[j*DKK + (c-10)];
    else if (c < 30) v = Wv[j*DKK + (c-20)];
    Wpack[idx] = v;
}

// ---------------------------------------------------------------- kernel 1
// Block 256 = 4 waves. lane = token (64 tok/block), wave = out-group of 8 cols
// (readfirstlane -> formally uniform -> W rows come in as batched s_loads).
// x staged TRANSPOSED in LDS: xs[dim][tok+1pad] -> compute reads are stride-1
// ds_read_b32 (2-way aliasing = free), staging writes ~2-way. No wide-conflict
// b128 reads (R3's 8-way) and no uncoalesced register path (R1/R5's stall).
__global__ __launch_bounds__(256) void proj_kernel(
    const float* __restrict__ x, const float* __restrict__ Wpack,
    const float* __restrict__ bq, const float* __restrict__ bk,
    const float* __restrict__ bv, float* __restrict__ qkv)
{
    __shared__ float xs[PC][65];        // 16.6 KB
    const int t    = threadIdx.x;
    const int lane = t & 63;
    const int grp  = __builtin_amdgcn_readfirstlane(t >> 6);  // 0..3 uniform
    const int tok0 = blockIdx.x*64;

    float acc[8];
    #pragma unroll
    for (int i=0;i<8;i++) acc[i]=0.f;

    for (int ch=0; ch<DIN/PC; ++ch){
        __syncthreads();
        // stage 64 tok x 64 dims (1024 float4, 4/thread), transposed into LDS
        #pragma unroll
        for (int p=0;p<4;p++){
            const int f  = t + p*256;
            const int tt = f >> 4;              // token 0..63
            const int dd = (f & 15) * 4;        // dim 0,4,..60
            const float4 v = *(const float4*)(x + (size_t)(tok0+tt)*DIN + ch*PC + dd);
            xs[dd+0][tt]=v.x; xs[dd+1][tt]=v.y; xs[dd+2][tt]=v.z; xs[dd+3][tt]=v.w;
        }
        __syncthreads();

        const float* wbase = Wpack + (size_t)(ch*PC)*32 + grp*8;
        for (int k=0;k<PC;k+=4){
            float w[4][8]; float xv[4];
            #pragma unroll
            for (int i=0;i<4;i++){
                xv[i] = xs[k+i][lane];
                #pragma unroll
                for (int o=0;o<8;o++) w[i][o] = wbase[(size_t)(k+i)*32+o];
            }
            #pragma unroll
            for (int i=0;i<4;i++){
                #pragma unroll
                for (int o=0;o<8;o++) acc[o] = fmaf(xv[i], w[i][o], acc[o]);
            }
        }
    }

    const float qs = 0.44721359549995793f;      // 1/sqrt(5) folded into Q
    const int tok = tok0 + lane;
    const int b   = tok >> 11;
    const int n   = tok & (NN-1);
    #pragma unroll
    for (int i=0;i<8;i++){
        const int c = grp*8 + i;
        if (c >= 30) continue;
        const int mat = c / 10;
        const int d10 = c - mat*10;
        const int h   = d10 / 5;
        const int dd  = d10 - h*5;
        float v = acc[i] + ((mat==0) ? bq[d10] : (mat==1) ? bk[d10] : bv[d10]);
        if (mat==0) v *= qs;
        qkv[(size_t)mat*BH*NN*8 + (((size_t)(b*NHD+h))*NN + n)*8 + dd] = v;
    }
}

// ---------------------------------------------------------------- kernel 2
// No LDS (K/V are L2-resident; R5's LDS staging was pure overhead).
// 2 q-rows per thread; K/V rows loaded in explicit 4-iter register batches
// BEFORE use (grouped loads -> one wait -> 272 VALU cycles per batch).
// scores = sin(q.k/sqrt5) in [-1,1] -> exp needs no max pass.
__global__ __launch_bounds__(256) void attn_kernel(
    const float* __restrict__ qkv, float* __restrict__ part)
{
    const int qt = blockIdx.x;          // 0..3 (512 q rows each)
    const int kc = blockIdx.y;          // 0..7
    const int bh = blockIdx.z;
    const int k0 = kc*KC;
    const int qb0 = qt*QB;
    if (k0 >= qb0 + QB) return;         // block-level causal early-out

    const int w    = threadIdx.x >> 6;  // 0..3
    const int lane = threadIdx.x & 63;
    const int qw0  = qb0 + w*128;       // this wave: q in [qw0, qw0+128)
    if (k0 >= qw0 + 128) return;        // wave-uniform early-out (no LDS/sync)

    const int q0 = qw0 + lane;
    const int q1 = qw0 + 64 + lane;
    const float* qr0 = qkv + ((size_t)bh*NN + q0)*8;
    const float* qr1 = qkv + ((size_t)bh*NN + q1)*8;
    const float4 qv0 = *(const float4*)qr0; const float q40 = qr0[4];
    const float4 qv1 = *(const float4*)qr1; const float q41 = qr1[4];

    const float* kb = qkv + (size_t)BH*NN*8 + (size_t)bh*NN*8;
    const float* vb = kb + (size_t)BH*NN*8;
    const int kend = min(KC, qw0 + 128 - k0);   // uniform, multiple of 128

    float d0=0,a00=0,a01=0,a02=0,a03=0,a04=0;
    float d1=0,a10=0,a11=0,a12=0,a13=0,a14=0;
    for (int kk=0; kk<kend; kk+=4){
        float4 K4[4], V4[4]; float K1[4], V1[4];
        #pragma unroll
        for (int i=0;i<4;i++){
            const float* kr = kb + (size_t)(k0+kk+i)*8;
            const float* vr = vb + (size_t)(k0+kk+i)*8;
            K4[i]=*(const float4*)kr; K1[i]=kr[4];
            V4[i]=*(const float4*)vr; V1[i]=vr[4];
        }
        #pragma unroll
        for (int i=0;i<4;i++){
            const int kg = k0+kk+i;
            float s0 = qv0.x*K4[i].x + qv0.y*K4[i].y + qv0.z*K4[i].z
                     + qv0.w*K4[i].w + q40*K1[i];
            float s1 = qv1.x*K4[i].x + qv1.y*K4[i].y + qv1.z*K4[i].z
                     + qv1.w*K4[i].w + q41*K1[i];
            float e0 = __expf(__sinf(s0));
            float e1 = __expf(__sinf(s1));
            e0 = (kg <= q0) ? e0 : 0.f;
            e1 = (kg <= q1) ? e1 : 0.f;
            d0 += e0;
            a00 = fmaf(e0, V4[i].x, a00);
            a01 = fmaf(e0, V4[i].y, a01);
            a02 = fmaf(e0, V4[i].z, a02);
            a03 = fmaf(e0, V4[i].w, a03);
            a04 = fmaf(e0, V1[i],   a04);
            d1 += e1;
            a10 = fmaf(e1, V4[i].x, a10);
            a11 = fmaf(e1, V4[i].y, a11);
            a12 = fmaf(e1, V4[i].z, a12);
            a13 = fmaf(e1, V4[i].w, a13);
            a14 = fmaf(e1, V1[i],   a14);
        }
    }
    float* pr0 = part + (((size_t)kc*BH + bh)*NN + q0)*8;
    *(float4*)pr0 = make_float4(a00,a01,a02,a03);
    pr0[4] = a04; pr0[5] = d0;
    float* pr1 = part + (((size_t)kc*BH + bh)*NN + q1)*8;
    *(float4*)pr1 = make_float4(a10,a11,a12,a13);
    pr1[4] = a14; pr1[5] = d1;
}

// ---------------------------------------------------------------- kernel 3a
// One TOKEN PER LANE: part-reduce + Wm1 + leaky_relu, write h1[tok][20].
__global__ __launch_bounds__(256) void h1_kernel(
    const float* __restrict__ part,
    const float* __restrict__ Wm1, const float* __restrict__ bm1,
    float* __restrict__ h1buf)
{
    const int tok = blockIdx.x*256 + threadIdx.x;   // 0..32767
    const int b   = tok >> 11;
    const int n   = tok & (NN-1);
    const int nc  = (n >> 8) + 1;                   // valid causal k-chunks

    float vals[DKK];
    #pragma unroll
    for (int h=0;h<NHD;h++){
        const int bh = b*NHD + h;
        float s0=0,s1=0,s2=0,s3=0,s4=0,sd=0;
        for (int c=0;c<nc;c++){
            const float* pr = part + (((size_t)c*BH + bh)*NN + n)*8;
            const float4 p0 = *(const float4*)pr;
            const float4 p1 = *(const float4*)(pr+4);
            s0+=p0.x; s1+=p0.y; s2+=p0.z; s3+=p0.w; s4+=p1.x; sd+=p1.y;
        }
        const float inv = 1.0f / sd;
        vals[h*DH+0]=s0*inv; vals[h*DH+1]=s1*inv; vals[h*DH+2]=s2*inv;
        vals[h*DH+3]=s3*inv; vals[h*DH+4]=s4*inv;
    }

    float h1[HID];
    #pragma unroll
    for (int jo=0;jo<HID;jo++){
        float t = bm1[jo];
        #pragma unroll
        for (int d=0;d<DKK;d++) t = fmaf(vals[d], Wm1[d*HID+jo], t);
        h1[jo] = (t > 0.f) ? t : 0.01f*t;
    }
    float* hr = h1buf + (size_t)tok*HID;            // 80B rows, 16B-aligned
    #pragma unroll
    for (int j5=0;j5<5;j5++)
        *(float4*)(hr + j5*4) = make_float4(h1[j5*4+0],h1[j5*4+1],h1[j5*4+2],h1[j5*4+3]);
}

// ---------------------------------------------------------------- kernel 3b
// One wave = half an output row (256 cols, 4/lane) for 8 tokens; Wm2 slice
// in registers; per token: 20 uniform h1 loads + 80 FMA + dwordx4 store.
__global__ __launch_bounds__(256) void out_kernel(
    const float* __restrict__ h1buf,
    const float* __restrict__ Wm2, const float* __restrict__ bm2,
    float* __restrict__ out)
{
    const int wave = threadIdx.x >> 6;
    const int lane = threadIdx.x & 63;
    const int unit = blockIdx.x*4 + wave;   // 0..8191
    const int hc   = unit & 1;
    const int tg   = unit >> 1;
    const int o0   = hc*256 + lane*4;

    float4 w2[HID];
    #pragma unroll
    for (int j=0;j<HID;j++) w2[j] = *(const float4*)(Wm2 + j*DOUT + o0);
    const float4 b2 = *(const float4*)(bm2 + o0);

    for (int ti=0; ti<8; ++ti){
        const int tok = tg*8 + ti;
        const float* hr = h1buf + (size_t)tok*HID;  // wave-uniform
        float4 acc = b2;
        #pragma unroll
        for (int j5=0;j5<5;j5++){
            const float4 hv = *(const float4*)(hr + j5*4);
            const float h0=hv.x, h1v=hv.y, h2=hv.z, h3=hv.w;
            acc.x = fmaf(h0, w2[j5*4+0].x, acc.x);
            acc.y = fmaf(h0, w2[j5*4+0].y, acc.y);
            acc.z = fmaf(h0, w2[j5*4+0].z, acc.z);
            acc.w = fmaf(h0, w2[j5*4+0].w, acc.w);
            acc.x = fmaf(h1v, w2[j5*4+1].x, acc.x);
            acc.y = fmaf(h1v, w2[j5*4+1].y, acc.y);
            acc.z = fmaf(h1v, w2[j5*4+1].z, acc.z);
            acc.w = fmaf(h1v, w2[j5*4+1].w, acc.w);
            acc.x = fmaf(h2, w2[j5*4+2].x, acc.x);
            acc.y = fmaf(h2, w2[j5*4+2].y, acc.y);
            acc.z = fmaf(h2, w2[j5*4+2].z, acc.z);
            acc.w = fmaf(h2, w2[j5*4+2].w, acc.w);
            acc.x = fmaf(h3, w2[j5*4+3].x, acc.x);
            acc.y = fmaf(h3, w2[j5*4+3].y, acc.y);
            acc.z = fmaf(h3, w2[j5*4+3].z, acc.z);
            acc.w = fmaf(h3, w2[j5*4+3].w, acc.w);
        }
        *(float4*)(out + (size_t)tok*DOUT + o0) = acc;
    }
}

// ---------------------------------------------------------------- launch
extern "C" void kernel_launch(void* const* d_in, const int* in_sizes, int n_in,
                              void* d_out, int out_size, void* d_ws, size_t ws_size,
                              hipStream_t stream) {
    const float* x   = (const float*)d_in[0];
    const float* Wq  = (const float*)d_in[1];
    const float* bq  = (const float*)d_in[2];
    const float* Wk  = (const float*)d_in[3];
    const float* bk  = (const float*)d_in[4];
    const float* Wv  = (const float*)d_in[5];
    const float* bv  = (const float*)d_in[6];
    const float* Wm1 = (const float*)d_in[7];
    const float* bm1 = (const float*)d_in[8];
    const float* Wm2 = (const float*)d_in[9];
    const float* bm2 = (const float*)d_in[10];
    float* out = (float*)d_out;

    float* qkv   = (float*)d_ws;
    float* part  = qkv + QKV_ELEMS;
    float* Wpack = part + PART_ELEMS;
    float* h1buf = qkv;   // overlays qkv: dead after attn_kernel (stream-ordered)

    pack_w_kernel<<<dim3(64), dim3(256), 0, stream>>>(Wq, Wk, Wv, Wpack);
    proj_kernel<<<dim3(512), dim3(256), 0, stream>>>(x, Wpack, bq, bk, bv, qkv);
    attn_kernel<<<dim3(4, NKC, BH), dim3(256), 0, stream>>>(qkv, part);
    h1_kernel<<<dim3(128), dim3(256), 0, stream>>>(part, Wm1, bm1, h1buf);
    out_kernel<<<dim3(2048), dim3(256), 0, stream>>>(h1buf, Wm2, bm2, out);
}